// Round 7
// baseline (1253.668 us; speedup 1.0000x reference)
//
#include <hip/hip_runtime.h>

typedef unsigned int uint;
typedef unsigned short ushort;
typedef __bf16 bf16x8 __attribute__((ext_vector_type(8)));
typedef float f32x4 __attribute__((ext_vector_type(4)));
typedef uint u32x4 __attribute__((ext_vector_type(4)));
typedef ushort u16x4 __attribute__((ext_vector_type(4)));

__device__ __forceinline__ float bf_lo(uint u) { return __builtin_bit_cast(float, u << 16); }
__device__ __forceinline__ float bf_hi(uint u) { return __builtin_bit_cast(float, u & 0xFFFF0000u); }
__device__ __forceinline__ ushort f2bf(float f) {
  uint u = __builtin_bit_cast(uint, f);
  return (ushort)((u + 0x7FFFu + ((u >> 16) & 1u)) >> 16);
}

// ---------------------------------------------------------------------------
// MFMA implicit-GEMM 3x3 conv, reflect-pad-1, bias, relu. NHWC bf16 bands.
// Weights prepacked [9][Co/16][Ci/32][lane64][8] bf16 (MFMA-native, coalesced).
// Block: 256 thr = 4 waves. Tile: 64co x 64px x ROWS rows. Wave: 64co x 16px.
// K-loop order: compute(c) THEN stage(c+1) — staging shares vmcnt with the
// A-frag loads, and vmcnt retires IN ORDER, so staging issued before compute
// would transitively block every A-frag wait (the round-6 835TF ceiling).
// compute is software-pipelined one tap ahead (rotating afr/bfr registers).
// ---------------------------------------------------------------------------
template<int NCH, int ROWS, int RELU>
__global__ __launch_bounds__(256) void conv_mfma_k(
    const ushort* __restrict__ in, const ushort* __restrict__ wp,
    const float* __restrict__ bias, ushort* __restrict__ out,
    int Cout, int H, int W,
    int in_row0, int in_rows, int out_row0, int out_rows,
    int ob_row0, int ob_rows) {
  constexpr int Cin = NCH * 32;
  constexpr int SLOTS = (ROWS + 2) * 66 * 4;      // 16B slots per buffer
  constexpr int NPASS = (SLOTS + 255) / 256;
  constexpr int LAST = SLOTS - (NPASS - 1) * 256; // active lanes in last pass
  __shared__ ushort lds[2][SLOTS * 8];
  const int tid = threadIdx.x;
  const int lane = tid & 63;
  const int wv = tid >> 6;
  const int wx0 = blockIdx.x * 64;
  const int nCoB = Cout >> 6;
  const int cob = (blockIdx.z % nCoB) * 64;
  const int b = blockIdx.z / nCoB;
  const int h0 = out_row0 + blockIdx.y * ROWS;
  const int nCb = Cout >> 4;
  const int cb0 = cob >> 4;

  // band rows: logical h0-1 .. h0+ROWS with image reflect, clamped to band
  int hs[ROWS + 2];
#pragma unroll
  for (int r = 0; r < ROWS + 2; ++r) {
    int hh = h0 - 1 + r;
    if (hh < 0) hh = 1;
    if (hh >= H) hh = 2 * (H - 1) - hh;
    hh = min(max(hh, in_row0), in_row0 + in_rows - 1);
    hs[r] = hh - in_row0;
  }

  // staging: slot t = (r*66+px)*4 + kg'
  const ushort* gsrc[NPASS];
  uint lof[NPASS];
#pragma unroll
  for (int p = 0; p < NPASS; ++p) {
    const int t = p * 256 + tid;
    const int px_g = t >> 2, kgs = t & 3;
    int rr = px_g / 66;
    int px = px_g - rr * 66;
    if (rr > ROWS + 1) { px = px_g - (ROWS + 2) * 66; rr = ROWS + 1; }
    const int kg = kgs ^ ((px >> 1) & 3);  // inverse swizzle on global source
    int wsrc = wx0 + px - 1;
    wsrc = (wsrc < 0) ? 1 : (wsrc >= W ? W - 2 : wsrc);
    gsrc[p] = in + ((size_t)(b * in_rows + hs[rr]) * W + wsrc) * Cin + kg * 8;
    lof[p] = (uint)((p * 256 + wv * 64) * 8);  // wave-uniform base (ushorts)
  }

  const int bpx = wv * 16 + (lane & 15);
  const int bkg = lane >> 4;

  f32x4 acc[ROWS][4] = {};

  auto stage = [&](int buf, int ci0) {
#pragma unroll
    for (int p = 0; p < NPASS; ++p) {
      if (p + 1 < NPASS || tid < LAST)
        __builtin_amdgcn_global_load_lds(
            (const __attribute__((address_space(1))) void*)(gsrc[p] + ci0),
            (__attribute__((address_space(3))) void*)(&lds[buf][lof[p]]), 16, 0, 0);
    }
  };
  auto compute = [&](int buf, int kc) {
    const ushort* lb = &lds[buf][0];
    u32x4 afr[2][4];
    u32x4 bfr[2][ROWS];
    // tap-0 prologue
#pragma unroll
    for (int ii = 0; ii < 4; ++ii)
      afr[0][ii] = *(const u32x4*)(wp + ((((0 * nCb + cb0 + ii) * NCH + kc) << 9) + (lane << 3)));
    {
      const int px = bpx;
      const int swz = bkg ^ ((px >> 1) & 3);
#pragma unroll
      for (int rr = 0; rr < ROWS; ++rr)
        bfr[0][rr] = *(const u32x4*)(lb + (((rr * 66 + px) << 2) + swz) * 8);
    }
#pragma unroll
    for (int t9 = 0; t9 < 9; ++t9) {
      const int cur = t9 & 1, nxt = cur ^ 1;
      if (t9 < 8) {  // prefetch tap t9+1 while t9's MFMAs run
        const int tn = t9 + 1;
        const int drn = tn / 3, sn = tn - drn * 3;
#pragma unroll
        for (int ii = 0; ii < 4; ++ii)
          afr[nxt][ii] = *(const u32x4*)(wp + ((((tn * nCb + cb0 + ii) * NCH + kc) << 9) + (lane << 3)));
        const int pxn = bpx + sn;
        const int swzn = bkg ^ ((pxn >> 1) & 3);
#pragma unroll
        for (int rr = 0; rr < ROWS; ++rr)
          bfr[nxt][rr] = *(const u32x4*)(lb + ((((rr + drn) * 66 + pxn) << 2) + swzn) * 8);
      }
#pragma unroll
      for (int rr = 0; rr < ROWS; ++rr) {
        const bf16x8 bb = __builtin_bit_cast(bf16x8, bfr[cur][rr]);
#pragma unroll
        for (int ii = 0; ii < 4; ++ii)
          acc[rr][ii] = __builtin_amdgcn_mfma_f32_16x16x32_bf16(
              __builtin_bit_cast(bf16x8, afr[cur][ii]), bb, acc[rr][ii], 0, 0, 0);
      }
    }
  };

  stage(0, 0);
  asm volatile("s_waitcnt vmcnt(0)" ::: "memory");
  __syncthreads();
#pragma unroll 1
  for (int c = 0; c < NCH; ++c) {
    compute(c & 1, c);
    if (c + 1 < NCH) stage((c + 1) & 1, (c + 1) * 32);
    asm volatile("s_waitcnt vmcnt(0)" ::: "memory");
    __syncthreads();
  }

  // epilogue: D col=lane&15 (px), row=(lane>>4)*4+reg (co within 16)
  const int cofr = cob + (lane >> 4) * 4;
  const int pxo = wx0 + bpx;
#pragma unroll
  for (int rr = 0; rr < ROWS; ++rr) {
    const int h = h0 + rr;
    if (h >= out_row0 + out_rows) break;
    const size_t base = ((size_t)(b * ob_rows + (h - ob_row0)) * W + pxo) * Cout;
#pragma unroll
    for (int ii = 0; ii < 4; ++ii) {
      u16x4 pk;
#pragma unroll
      for (int g = 0; g < 4; ++g) {
        float v = acc[rr][ii][g] + bias[cofr + ii * 16 + g];
        if (RELU) v = fmaxf(v, 0.f);
        pk[g] = f2bf(v);
      }
      *(u16x4*)(out + base + cofr + ii * 16) = pk;
    }
  }
}

// ---------------------------------------------------------------------------
// final conv 64->3 via MFMA with Cout padded to 16 (rows 3..15 zero).
// Same staging as conv_mfma_k (Cin=64, ROWS=4). Output f32 NCHW to d_out.
// ---------------------------------------------------------------------------
__global__ __launch_bounds__(256) void convf_mfma_k(
    const ushort* __restrict__ in, const ushort* __restrict__ wp,
    const float* __restrict__ bias, float* __restrict__ out,
    int in_row0, int in_rows, int out_row0, int out_rows) {
  constexpr int ROWS = 4, NCH = 2, W = 512, H = 512, Cin = 64;
  constexpr int SLOTS = (ROWS + 2) * 66 * 4;
  constexpr int NPASS = (SLOTS + 255) / 256;
  constexpr int LAST = SLOTS - (NPASS - 1) * 256;
  __shared__ ushort lds[2][SLOTS * 8];
  const int tid = threadIdx.x;
  const int lane = tid & 63;
  const int wv = tid >> 6;
  const int wx0 = blockIdx.x * 64;
  const int b = blockIdx.z;
  const int h0 = out_row0 + blockIdx.y * ROWS;

  int hs[ROWS + 2];
#pragma unroll
  for (int r = 0; r < ROWS + 2; ++r) {
    int hh = h0 - 1 + r;
    if (hh < 0) hh = 1;
    if (hh >= H) hh = 2 * (H - 1) - hh;
    hh = min(max(hh, in_row0), in_row0 + in_rows - 1);
    hs[r] = hh - in_row0;
  }
  const ushort* gsrc[NPASS];
  uint lof[NPASS];
#pragma unroll
  for (int p = 0; p < NPASS; ++p) {
    const int t = p * 256 + tid;
    const int px_g = t >> 2, kgs = t & 3;
    int rr = px_g / 66;
    int px = px_g - rr * 66;
    if (rr > ROWS + 1) { px = px_g - (ROWS + 2) * 66; rr = ROWS + 1; }
    const int kg = kgs ^ ((px >> 1) & 3);
    int wsrc = wx0 + px - 1;
    wsrc = (wsrc < 0) ? 1 : (wsrc >= W ? W - 2 : wsrc);
    gsrc[p] = in + ((size_t)(b * in_rows + hs[rr]) * W + wsrc) * Cin + kg * 8;
    lof[p] = (uint)((p * 256 + wv * 64) * 8);
  }
  const int bpx = wv * 16 + (lane & 15);
  const int bkg = lane >> 4;
  f32x4 acc[ROWS] = {};

  auto stage = [&](int buf, int ci0) {
#pragma unroll
    for (int p = 0; p < NPASS; ++p) {
      if (p + 1 < NPASS || tid < LAST)
        __builtin_amdgcn_global_load_lds(
            (const __attribute__((address_space(1))) void*)(gsrc[p] + ci0),
            (__attribute__((address_space(3))) void*)(&lds[buf][lof[p]]), 16, 0, 0);
    }
  };
  auto compute = [&](int buf, int kc) {
    const ushort* lb = &lds[buf][0];
    u32x4 afr[2];
    u32x4 bfr[2][ROWS];
    afr[0] = *(const u32x4*)(wp + (((0 * NCH + kc) << 9) + (lane << 3)));
    {
      const int px = bpx;
      const int swz = bkg ^ ((px >> 1) & 3);
#pragma unroll
      for (int rr = 0; rr < ROWS; ++rr)
        bfr[0][rr] = *(const u32x4*)(lb + (((rr * 66 + px) << 2) + swz) * 8);
    }
#pragma unroll
    for (int t9 = 0; t9 < 9; ++t9) {
      const int cur = t9 & 1, nxt = cur ^ 1;
      if (t9 < 8) {
        const int tn = t9 + 1;
        const int drn = tn / 3, sn = tn - drn * 3;
        afr[nxt] = *(const u32x4*)(wp + (((tn * NCH + kc) << 9) + (lane << 3)));
        const int pxn = bpx + sn;
        const int swzn = bkg ^ ((pxn >> 1) & 3);
#pragma unroll
        for (int rr = 0; rr < ROWS; ++rr)
          bfr[nxt][rr] = *(const u32x4*)(lb + ((((rr + drn) * 66 + pxn) << 2) + swzn) * 8);
      }
#pragma unroll
      for (int rr = 0; rr < ROWS; ++rr)
        acc[rr] = __builtin_amdgcn_mfma_f32_16x16x32_bf16(
            __builtin_bit_cast(bf16x8, afr[cur]),
            __builtin_bit_cast(bf16x8, bfr[cur][rr]), acc[rr], 0, 0, 0);
    }
  };

  stage(0, 0);
  asm volatile("s_waitcnt vmcnt(0)" ::: "memory");
  __syncthreads();
#pragma unroll 1
  for (int c = 0; c < NCH; ++c) {
    compute(c & 1, c);
    if (c + 1 < NCH) stage((c + 1) & 1, (c + 1) * 32);
    asm volatile("s_waitcnt vmcnt(0)" ::: "memory");
    __syncthreads();
  }

  if ((lane >> 4) == 0) {  // co rows 0..3 hold channels 0..2
    const int pxo = wx0 + bpx;
#pragma unroll
    for (int rr = 0; rr < ROWS; ++rr) {
      const int h = h0 + rr;
      if (h >= out_row0 + out_rows) break;
#pragma unroll
      for (int g = 0; g < 3; ++g)
        out[(((size_t)(b * 3 + g)) << 18) + ((size_t)h << 9) + pxo] = acc[rr][g] + bias[g];
    }
  }
}

// ---------------------------------------------------------------------------
// seg-norm stats: per (b, class, channel) sums via atomics. NHWC bf16 input.
// ---------------------------------------------------------------------------
__global__ __launch_bounds__(256) void sn_sum_k(
    const ushort* __restrict__ x, const int* __restrict__ seg,
    float* __restrict__ Ssum, float* __restrict__ Qsum, int C, int logW, int nsl) {
  const int W = 1 << logW, sh = logW - 6;
  const int b = blockIdx.x / nsl, sl = blockIdx.x % nsl;
  const int PPT = 256 / C;
  const int c = threadIdx.x % C;
  const int sub = threadIdx.x / C;
  const int rows = W / nsl;
  const int p0 = sl * rows * W;
  const int np = rows * W;
  const ushort* xp = x + ((size_t)b << (2 * logW)) * C + (size_t)p0 * C;
  const int* segb = seg + (b << 12);
  float S[8] = {0, 0, 0, 0, 0, 0, 0, 0};
  float Q[8] = {0, 0, 0, 0, 0, 0, 0, 0};
  for (int k = sub; k < np; k += PPT) {
    const int p = p0 + k;
    const int cls = segb[(((p >> logW) >> sh) << 6) + ((p & (W - 1)) >> sh)];
    const uint u = xp[(size_t)k * C + c];
    const float v = __builtin_bit_cast(float, u << 16);
#pragma unroll
    for (int t = 0; t < 8; ++t) {
      const bool m = (cls == t);
      S[t] += m ? v : 0.f;
      Q[t] += m ? v * v : 0.f;
    }
  }
#pragma unroll
  for (int t = 0; t < 8; ++t) {
    atomicAdd(&Ssum[((b << 3) + t) * C + c], S[t]);
    atomicAdd(&Qsum[((b << 3) + t) * C + c], Q[t]);
  }
}

__global__ void sn_fin_k(const float* __restrict__ Ssum, const float* __restrict__ Qsum,
                         float* __restrict__ RS, float* __restrict__ KK, int C, float invN) {
  const int tid = threadIdx.x;
  const int b = tid / C, c = tid % C;
  float K = 0.f;
#pragma unroll
  for (int t = 0; t < 8; ++t) {
    const float s = Ssum[((b << 3) + t) * C + c];
    const float q = Qsum[((b << 3) + t) * C + c];
    const float mu = s * invN;
    const float var = q * invN - mu * mu;
    const float r = rsqrtf(var + 1e-5f);
    RS[((b << 3) + t) * C + c] = r;
    K += mu * r;
  }
  KK[b * C + c] = K;
}

// ---------------------------------------------------------------------------
// fused seg-norm apply + bilinear 2x upsample. src NHWC bf16 full (Ws x Ws),
// writes band rows [out_row0, out_row0+out_rows) at 2Ws. 8 channels/thread.
// ---------------------------------------------------------------------------
__global__ __launch_bounds__(256) void up2norm_k(
    const ushort* __restrict__ src, const int* __restrict__ seg,
    const float* __restrict__ RS, const float* __restrict__ KK,
    ushort* __restrict__ out, int C, int logWs, int out_row0, int out_rows) {
  const int Ws = 1 << logWs, W2 = Ws << 1, sh = logWs - 6;
  const int cpb = C >> 3;
  int i = blockIdx.x * 256 + threadIdx.x;
  const int total = 4 * out_rows * W2 * cpb;
  if (i >= total) return;
  const int cc = (i % cpb) * 8; i /= cpb;
  const int ow = i % W2; i /= W2;
  const int r = i % out_rows;
  const int b = i / out_rows;
  const int oh = out_row0 + r;

  int hl = (oh - 1) >> 1;
  const float hf = (oh & 1) ? 0.25f : 0.75f;
  const int hh = min(hl + 1, Ws - 1);
  hl = max(hl, 0);
  int wl = (ow - 1) >> 1;
  const float wfc = (ow & 1) ? 0.25f : 0.75f;
  const int wh = min(wl + 1, Ws - 1);
  wl = max(wl, 0);

  const size_t pl = (size_t)b << (2 * logWs);
  const u32x4 xll = *(const u32x4*)(src + ((pl + hl * Ws + wl) * C + cc));
  const u32x4 xlh = *(const u32x4*)(src + ((pl + hl * Ws + wh) * C + cc));
  const u32x4 xhl = *(const u32x4*)(src + ((pl + hh * Ws + wl) * C + cc));
  const u32x4 xhh = *(const u32x4*)(src + ((pl + hh * Ws + wh) * C + cc));
  const int* segb = seg + (b << 12);
  const int cll = segb[((hl >> sh) << 6) + (wl >> sh)];
  const int clh = segb[((hl >> sh) << 6) + (wh >> sh)];
  const int chl = segb[((hh >> sh) << 6) + (wl >> sh)];
  const int chh = segb[((hh >> sh) << 6) + (wh >> sh)];
  const float* rll = RS + ((b << 3) + cll) * C + cc;
  const float* rlh = RS + ((b << 3) + clh) * C + cc;
  const float* rhl = RS + ((b << 3) + chl) * C + cc;
  const float* rhh = RS + ((b << 3) + chh) * C + cc;
  const float* kk = KK + b * C + cc;

  u32x4 res;
#pragma unroll
  for (int q = 0; q < 4; ++q) {
    const int c0 = 2 * q, c1 = 2 * q + 1;
    const float na0 = bf_lo(xll[q]) * rll[c0], nb0 = bf_lo(xlh[q]) * rlh[c0];
    const float nc0 = bf_lo(xhl[q]) * rhl[c0], nd0 = bf_lo(xhh[q]) * rhh[c0];
    const float na1 = bf_hi(xll[q]) * rll[c1], nb1 = bf_hi(xlh[q]) * rlh[c1];
    const float nc1 = bf_hi(xhl[q]) * rhl[c1], nd1 = bf_hi(xhh[q]) * rhh[c1];
    const float t0 = na0 + wfc * (nb0 - na0), bo0 = nc0 + wfc * (nd0 - nc0);
    const float t1 = na1 + wfc * (nb1 - na1), bo1 = nc1 + wfc * (nd1 - nc1);
    const float o0 = t0 + hf * (bo0 - t0) - kk[c0];
    const float o1 = t1 + hf * (bo1 - t1) - kk[c1];
    res[q] = (uint)f2bf(o0) | ((uint)f2bf(o1) << 16);
  }
  *(u32x4*)(out + (((size_t)(b * out_rows + r)) * W2 + ow) * C + cc) = res;
}

// ---------------------------------------------------------------------------
// fused weight pack: all 8 intermediate convs in one launch.
// [Co][Ci][3][3] f32 -> [9][Co/16][Ci/32][lane64][8] bf16
// ---------------------------------------------------------------------------
struct PWSeg { const float* w; ushort* p; int Co, Ci; };
struct PackArgs { PWSeg s[8]; };
__global__ __launch_bounds__(256) void packall_k(PackArgs a) {
  int i = blockIdx.x * 256 + threadIdx.x;
#pragma unroll
  for (int k = 0; k < 8; ++k) {
    const int Co = a.s[k].Co, Ci = a.s[k].Ci;
    const int tot = Co * Ci * 9;
    if (i < tot) {
      const int nKc = Ci >> 5, nCb = Co >> 4;
      const int j = i & 7, l = (i >> 3) & 63;
      int rest = i >> 9;
      const int kc = rest % nKc; rest /= nKc;
      const int cb = rest % nCb;
      const int t9 = rest / nCb;
      const int co = cb * 16 + (l & 15);
      const int ci = kc * 32 + (l >> 4) * 8 + j;
      a.s[k].p[i] = f2bf(a.s[k].w[((size_t)(co * Ci + ci)) * 9 + t9]);
      return;
    }
    i -= tot;
  }
}

// wf [3][64][3][3] f32 -> [9][2][lane64][8] bf16 with Co padded 3->16 (zeros)
__global__ __launch_bounds__(256) void packwf_k(const float* __restrict__ w,
                                                ushort* __restrict__ wp) {
  const int i = blockIdx.x * 256 + threadIdx.x;
  if (i >= 9216) return;
  const int j = i & 7;
  const int l = (i >> 3) & 63;
  const int rest = i >> 9;
  const int kc = rest & 1;
  const int t9 = rest >> 1;
  const int co = l & 15;
  const int ci = kc * 32 + (l >> 4) * 8 + j;
  wp[i] = (co < 3) ? f2bf(w[((size_t)(co * 64 + ci)) * 9 + t9]) : (ushort)0;
}

// x f32 NCHW (4,512,64,64) -> bf16 NHWC via LDS transpose (32c x 64p tiles)
__global__ __launch_bounds__(256) void cvt_x_k(const float* __restrict__ x,
                                               ushort* __restrict__ xn) {
  __shared__ float tile[32][65];
  const int p0 = blockIdx.x * 64, c0 = blockIdx.y * 32, b = blockIdx.z;
  for (int k = threadIdx.x; k < 2048; k += 256) {
    const int ci = k >> 6, pj = k & 63;
    tile[ci][pj] = x[(((size_t)(b * 512 + c0 + ci)) << 12) + p0 + pj];
  }
  __syncthreads();
  for (int k = threadIdx.x; k < 2048; k += 256) {
    const int ci = k & 31, pj = k >> 5;
    xn[((((size_t)b << 12) + p0 + pj)) * 512 + c0 + ci] = f2bf(tile[ci][pj]);
  }
}

// ---------------------------------------------------------------------------
extern "C" void kernel_launch(void* const* d_in, const int* in_sizes, int n_in,
                              void* d_out, int out_size, void* d_ws, size_t ws_size,
                              hipStream_t stream) {
  const float* x = (const float*)d_in[0];
  const int* seg = (const int*)d_in[1];
  const float *w1 = (const float*)d_in[2], *b1 = (const float*)d_in[3];
  const float *w2 = (const float*)d_in[4], *b2 = (const float*)d_in[5];
  const float *w3 = (const float*)d_in[6], *b3 = (const float*)d_in[7];
  const float *w4 = (const float*)d_in[8], *b4 = (const float*)d_in[9];
  const float *w5 = (const float*)d_in[10], *b5 = (const float*)d_in[11];
  const float *w6 = (const float*)d_in[12], *b6 = (const float*)d_in[13];
  const float *w7 = (const float*)d_in[14], *b7 = (const float*)d_in[15];
  const float *w8 = (const float*)d_in[16], *b8 = (const float*)d_in[17];
  const float *wf = (const float*)d_in[18], *bf = (const float*)d_in[19];
  float* outp = (float*)d_out;

  char* wsb = (char*)d_ws;
  const size_t MB = 1048576;
  ushort* w1p = (ushort*)(wsb + 0);
  ushort* w2p = (ushort*)(wsb + 2359296);
  ushort* w3p = (ushort*)(wsb + 3538944);
  ushort* w4p = (ushort*)(wsb + 4718592);
  ushort* w5p = (ushort*)(wsb + 5898240);
  ushort* w6p = (ushort*)(wsb + 6488064);
  ushort* w7p = (ushort*)(wsb + 6782976);
  ushort* w8p = (ushort*)(wsb + 6930432);
  ushort* wfp = (ushort*)(wsb + 7004160);
  float* Ssum = (float*)(wsb + 8388608);
  float* Qsum = (float*)(wsb + 8421376);
  float* RS = (float*)(wsb + 8454144);
  float* KK = (float*)(wsb + 8486912);
  // activation arenas (all bf16 NHWC); lifetimes verified disjoint:
  ushort* XN = (ushort*)(wsb + 9 * MB);   // (4,64,64,512)    16MB  [9,25)
  ushort* A1 = (ushort*)(wsb + 25 * MB);  // (4,64,64,256)     8MB  [25,33)
  ushort* U1 = (ushort*)(wsb + 33 * MB);  // (4,128,128,256)  32MB  [33,65)
  ushort* C2 = (ushort*)(wsb + 65 * MB);  // 32MB                   [65,97)
  ushort* C3 = (ushort*)(wsb + 9 * MB);   // 32MB (XN/A1 dead)      [9,41)
  ushort* C4 = (ushort*)(wsb + 41 * MB);  // 32MB (U1/C2 dead)      [41,73)
  ushort* C5 = (ushort*)(wsb + 9 * MB);   // (4,128,128,128)  16MB  [9,25)
  ushort* U6 = (ushort*)(wsb + 25 * MB);  // band <=130 rows 32.5MB [25,58)
  ushort* C6 = (ushort*)(wsb + 58 * MB);  // band <=129 rows 32.3MB [58,91)
  ushort* C7 = (ushort*)(wsb + 91 * MB);  // (4,256,256,64)   32MB  [91,123)
  ushort* U8 = (ushort*)(wsb + 9 * MB);   // band <=132 rows 33MB   [9,43)
  ushort* C8 = (ushort*)(wsb + 43 * MB);  // band <=130 rows 32.5MB [43,76)

  auto cdiv = [](int a, int b) { return (a + b - 1) / b; };

  // weight packs + input conversion
  cvt_x_k<<<dim3(64, 16, 4), 256, 0, stream>>>(x, XN);
  PackArgs pa;
  pa.s[0] = {w1, w1p, 256, 512};
  pa.s[1] = {w2, w2p, 256, 256};
  pa.s[2] = {w3, w3p, 256, 256};
  pa.s[3] = {w4, w4p, 256, 256};
  pa.s[4] = {w5, w5p, 128, 256};
  pa.s[5] = {w6, w6p, 128, 128};
  pa.s[6] = {w7, w7p, 64, 128};
  pa.s[7] = {w8, w8p, 64, 64};
  packall_k<<<cdiv(3502080, 256), 256, 0, stream>>>(pa);
  packwf_k<<<36, 256, 0, stream>>>(wf, wfp);

  // ---- @64 ----
  conv_mfma_k<16, 2, 1><<<dim3(1, 32, 16), 256, 0, stream>>>(
      XN, w1p, b1, A1, 256, 64, 64, 0, 64, 0, 64, 0, 64);
  hipMemsetAsync(Ssum, 0, 65536, stream);
  sn_sum_k<<<4 * 32, 256, 0, stream>>>(A1, seg, Ssum, Qsum, 256, 6, 32);
  sn_fin_k<<<1, 1024, 0, stream>>>(Ssum, Qsum, RS, KK, 256, 1.f / 4096.f);
  up2norm_k<<<cdiv(4 * 128 * 128 * 32, 256), 256, 0, stream>>>(A1, seg, RS, KK, U1, 256, 6, 0, 128);

  // ---- @128 ----
  conv_mfma_k<8, 4, 1><<<dim3(2, 32, 16), 256, 0, stream>>>(
      U1, w2p, b2, C2, 256, 128, 128, 0, 128, 0, 128, 0, 128);
  conv_mfma_k<8, 4, 1><<<dim3(2, 32, 16), 256, 0, stream>>>(
      C2, w3p, b3, C3, 256, 128, 128, 0, 128, 0, 128, 0, 128);
  conv_mfma_k<8, 4, 1><<<dim3(2, 32, 16), 256, 0, stream>>>(
      C3, w4p, b4, C4, 256, 128, 128, 0, 128, 0, 128, 0, 128);
  conv_mfma_k<8, 4, 1><<<dim3(2, 32, 8), 256, 0, stream>>>(
      C4, w5p, b5, C5, 128, 128, 128, 0, 128, 0, 128, 0, 128);
  hipMemsetAsync(Ssum, 0, 65536, stream);
  sn_sum_k<<<4 * 64, 256, 0, stream>>>(C5, seg, Ssum, Qsum, 128, 7, 64);
  sn_fin_k<<<1, 512, 0, stream>>>(Ssum, Qsum, RS, KK, 128, 1.f / 16384.f);

  // ---- @256, 2 bands: up2norm -> conv6 -> conv7 ----
  for (int kb = 0; kb < 2; ++kb) {
    const int r0 = kb * 128;
    const int Rlo = max(r0 - 1, 0), Rhi = min(r0 + 128, 255);
    const int rows6 = Rhi - Rlo + 1;
    const int Ulo = max(Rlo - 1, 0), Uhi = min(Rhi + 1, 255);
    const int rowsU = Uhi - Ulo + 1;
    up2norm_k<<<cdiv(4 * rowsU * 256 * 16, 256), 256, 0, stream>>>(C5, seg, RS, KK, U6, 128, 7, Ulo, rowsU);
    conv_mfma_k<4, 4, 1><<<dim3(4, cdiv(rows6, 4), 8), 256, 0, stream>>>(
        U6, w6p, b6, C6, 128, 256, 256, Ulo, rowsU, Rlo, rows6, Rlo, rows6);
    conv_mfma_k<4, 4, 1><<<dim3(4, 32, 4), 256, 0, stream>>>(
        C6, w7p, b7, C7, 64, 256, 256, Rlo, rows6, r0, 128, 0, 256);
  }
  hipMemsetAsync(Ssum, 0, 65536, stream);
  sn_sum_k<<<4 * 128, 256, 0, stream>>>(C7, seg, Ssum, Qsum, 64, 8, 128);
  sn_fin_k<<<1, 256, 0, stream>>>(Ssum, Qsum, RS, KK, 64, 1.f / 65536.f);

  // ---- @512, 4 bands: up2norm -> conv8 -> convf ----
  for (int kb = 0; kb < 4; ++kb) {
    const int r0 = kb * 128;
    const int Rlo = max(r0 - 1, 0), Rhi = min(r0 + 128, 511);
    const int rows8 = Rhi - Rlo + 1;
    const int Ulo = max(Rlo - 1, 0), Uhi = min(Rhi + 1, 511);
    const int rowsU = Uhi - Ulo + 1;
    up2norm_k<<<cdiv(4 * rowsU * 512 * 8, 256), 256, 0, stream>>>(C7, seg, RS, KK, U8, 64, 8, Ulo, rowsU);
    conv_mfma_k<2, 4, 1><<<dim3(8, cdiv(rows8, 4), 4), 256, 0, stream>>>(
        U8, w8p, b8, C8, 64, 512, 512, Ulo, rowsU, Rlo, rows8, Rlo, rows8);
    convf_mfma_k<<<dim3(8, 32, 4), 256, 0, stream>>>(C8, wfp, bf, outp, Rlo, rows8, r0, 128);
  }
}